// Round 1
// baseline (784.661 us; speedup 1.0000x reference)
//
#include <hip/hip_runtime.h>
#include <hip/hip_fp16.h>

#define DD 1024
#define LL 128
#define NSEG 64

typedef _Float16 half8 __attribute__((ext_vector_type(8)));
typedef _Float16 half4v __attribute__((ext_vector_type(4)));
typedef float floatx4 __attribute__((ext_vector_type(4)));

// ---------------- prep: convert Wa|Wb -> f16 Wab [256][1024], zero seg buffers ----
__global__ __launch_bounds__(256)
void prep_kernel(const float* __restrict__ Wa, const float* __restrict__ Wb,
                 _Float16* __restrict__ Wab, unsigned* __restrict__ smaxu,
                 float* __restrict__ denom)
{
    int gid = blockIdx.x * 256 + threadIdx.x;
    if (gid < LL * DD)            Wab[gid] = (_Float16)Wa[gid];
    else if (gid < 2 * LL * DD)   Wab[gid] = (_Float16)Wb[gid - LL * DD];
    if (gid < NSEG)               smaxu[gid] = 0u;
    else if (gid < 2 * NSEG)      denom[gid - NSEG] = 0.0f;
}

// ---------------- fused: normalize + dual GEMM + gate + Wc dot -> raw scores ----
__global__ __launch_bounds__(256, 2)
void fused_main(const float* __restrict__ feat,
                const _Float16* __restrict__ Wab,
                const float* __restrict__ ba,
                const float* __restrict__ bb,
                const float* __restrict__ Wc,
                const float* __restrict__ bc,
                float* __restrict__ out_norm,
                float* __restrict__ score_raw)
{
    __shared__ __align__(16) char tile[32 * 2048];   // 32 rows x 1024 f16, XOR-swizzled (64 KB)
    __shared__ float scorebuf[32];

    const int tid  = threadIdx.x;
    const int wave = tid >> 6;
    const int lane = tid & 63;
    const long long row0 = (long long)blockIdx.x * 32;

    if (tid < 32) scorebuf[tid] = 0.0f;

    // ---------------- Phase A: stream rows, norm, write out, stage f16 tile ----
    {
        const int rbase = wave * 8;                       // this wave's local rows
        const float4* src = reinterpret_cast<const float4*>(feat) + (row0 + rbase) * (DD / 4) + lane;
        float4 cur[4];
        cur[0] = src[0]; cur[1] = src[64]; cur[2] = src[128]; cur[3] = src[192];
        #pragma unroll
        for (int r = 0; r < 8; ++r) {
            float4 nxt[4];
            if (r < 7) {
                const float4* s2 = src + (long long)(r + 1) * (DD / 4);
                nxt[0] = s2[0]; nxt[1] = s2[64]; nxt[2] = s2[128]; nxt[3] = s2[192];
            }
            const int lrow = rbase + r;
            float ss = cur[0].x*cur[0].x + cur[0].y*cur[0].y + cur[0].z*cur[0].z + cur[0].w*cur[0].w;
            ss += cur[1].x*cur[1].x + cur[1].y*cur[1].y + cur[1].z*cur[1].z + cur[1].w*cur[1].w;
            ss += cur[2].x*cur[2].x + cur[2].y*cur[2].y + cur[2].z*cur[2].z + cur[2].w*cur[2].w;
            ss += cur[3].x*cur[3].x + cur[3].y*cur[3].y + cur[3].z*cur[3].z + cur[3].w*cur[3].w;
            #pragma unroll
            for (int off = 32; off >= 1; off >>= 1) ss += __shfl_xor(ss, off);
            const float rinv = 1.0f / fmaxf(sqrtf(ss), 1e-12f);

            float4* dst = reinterpret_cast<float4*>(out_norm) + (row0 + lrow) * (DD / 4) + lane;
            #pragma unroll
            for (int c = 0; c < 4; ++c) {
                float4 v;
                v.x = cur[c].x * rinv; v.y = cur[c].y * rinv;
                v.z = cur[c].z * rinv; v.w = cur[c].w * rinv;
                dst[c * 64] = v;
            }
            const int swz = (lrow & 7) << 4;
            #pragma unroll
            for (int c = 0; c < 4; ++c) {
                half4v h;
                h[0] = (_Float16)cur[c].x; h[1] = (_Float16)cur[c].y;
                h[2] = (_Float16)cur[c].z; h[3] = (_Float16)cur[c].w;
                const int boff = lrow * 2048 + ((c * 512 + lane * 8) ^ swz);
                *reinterpret_cast<half4v*>(tile + boff) = h;
            }
            cur[0] = nxt[0]; cur[1] = nxt[1]; cur[2] = nxt[2]; cur[3] = nxt[3];
        }
    }
    __syncthreads();

    // ---------------- Phase B: MFMA dual GEMM over K=1024 ----
    const int llo = lane & 15;
    const int lhi = lane >> 4;
    floatx4 acc_a[2][2];
    floatx4 acc_b[2][2];
    #pragma unroll
    for (int rt = 0; rt < 2; ++rt)
        #pragma unroll
        for (int ct = 0; ct < 2; ++ct) { acc_a[rt][ct] = (floatx4)0.0f; acc_b[rt][ct] = (floatx4)0.0f; }

    const int colA0 = wave * 32 + llo;   // column within [0,128): + ct*16

    #pragma unroll 2
    for (int ks = 0; ks < 32; ++ks) {
        half8 af[2];
        #pragma unroll
        for (int rt = 0; rt < 2; ++rt) {
            const int lrow = rt * 16 + llo;
            const int boff = lrow * 2048 + ((ks * 64 + lhi * 16) ^ ((lrow & 7) << 4));
            af[rt] = *reinterpret_cast<const half8*>(tile + boff);
        }
        half8 bfa[2], bfb[2];
        #pragma unroll
        for (int ct = 0; ct < 2; ++ct) {
            bfa[ct] = *reinterpret_cast<const half8*>(Wab + (size_t)(colA0 + ct * 16) * DD + ks * 32 + lhi * 8);
            bfb[ct] = *reinterpret_cast<const half8*>(Wab + (size_t)(LL + colA0 + ct * 16) * DD + ks * 32 + lhi * 8);
        }
        #pragma unroll
        for (int rt = 0; rt < 2; ++rt)
            #pragma unroll
            for (int ct = 0; ct < 2; ++ct) {
                acc_a[rt][ct] = __builtin_amdgcn_mfma_f32_16x16x32_f16(af[rt], bfa[ct], acc_a[rt][ct], 0, 0, 0);
                acc_b[rt][ct] = __builtin_amdgcn_mfma_f32_16x16x32_f16(af[rt], bfb[ct], acc_b[rt][ct], 0, 0, 0);
            }
    }

    // ---------------- epilogue: sigmoid(a)*tanh(b) . Wc -> per-row score ----
    float wcv[2], bav[2], bbv[2];
    #pragma unroll
    for (int ct = 0; ct < 2; ++ct) {
        const int c = colA0 + ct * 16;          // 0..127
        wcv[ct] = Wc[c]; bav[ct] = ba[c]; bbv[ct] = bb[c];
    }
    #pragma unroll
    for (int rt = 0; rt < 2; ++rt) {
        float s[4] = {0.f, 0.f, 0.f, 0.f};
        #pragma unroll
        for (int ct = 0; ct < 2; ++ct)
            #pragma unroll
            for (int j = 0; j < 4; ++j) {
                const float av = 1.0f / (1.0f + expf(-(acc_a[rt][ct][j] + bav[ct])));
                const float bv = tanhf(acc_b[rt][ct][j] + bbv[ct]);
                s[j] += av * bv * wcv[ct];
            }
        #pragma unroll
        for (int j = 0; j < 4; ++j) {
            s[j] += __shfl_xor(s[j], 1);
            s[j] += __shfl_xor(s[j], 2);
            s[j] += __shfl_xor(s[j], 4);
            s[j] += __shfl_xor(s[j], 8);
        }
        if (llo == 0) {
            #pragma unroll
            for (int j = 0; j < 4; ++j)
                atomicAdd(&scorebuf[rt * 16 + lhi * 4 + j], s[j]);
        }
    }
    __syncthreads();
    if (tid < 32) score_raw[row0 + tid] = scorebuf[tid] + bc[0];
}

// ---------------- segment softmax (3 tiny passes over N floats) ----------------
__global__ __launch_bounds__(256)
void seg_max_kernel(const float* __restrict__ score, const int* __restrict__ batch,
                    unsigned* __restrict__ smaxu, int n)
{
    __shared__ unsigned sm[NSEG];
    const int t = threadIdx.x;
    if (t < NSEG) sm[t] = 0u;
    __syncthreads();
    const int stride = gridDim.x * blockDim.x;
    for (int i = blockIdx.x * blockDim.x + t; i < n; i += stride) {
        const unsigned b = __float_as_uint(score[i]);
        const unsigned m = (b & 0x80000000u) ? ~b : (b | 0x80000000u);
        atomicMax(&sm[batch[i]], m);
    }
    __syncthreads();
    if (t < NSEG) atomicMax(&smaxu[t], sm[t]);
}

__global__ __launch_bounds__(256)
void seg_exp_kernel(float* __restrict__ score_inout, const int* __restrict__ batch,
                    const unsigned* __restrict__ smaxu, float* __restrict__ denom, int n)
{
    __shared__ float sd[NSEG];
    __shared__ float smx[NSEG];
    const int t = threadIdx.x;
    if (t < NSEG) {
        sd[t] = 0.0f;
        const unsigned u = smaxu[t];
        const unsigned b = (u & 0x80000000u) ? (u ^ 0x80000000u) : ~u;
        smx[t] = __uint_as_float(b);
    }
    __syncthreads();
    const int stride = gridDim.x * blockDim.x;
    for (int i = blockIdx.x * blockDim.x + t; i < n; i += stride) {
        const int b = batch[i];
        const float e = expf(score_inout[i] - smx[b]);
        score_inout[i] = e;
        atomicAdd(&sd[b], e);
    }
    __syncthreads();
    if (t < NSEG) atomicAdd(&denom[t], sd[t]);
}

__global__ __launch_bounds__(256)
void seg_div_kernel(float* __restrict__ score_inout, const int* __restrict__ batch,
                    const float* __restrict__ denom, int n)
{
    const int stride = gridDim.x * blockDim.x;
    for (int i = blockIdx.x * blockDim.x + threadIdx.x; i < n; i += stride)
        score_inout[i] = score_inout[i] / (denom[batch[i]] + 1e-16f);
}

// ---------------------------------------------------------------------------
extern "C" void kernel_launch(void* const* d_in, const int* in_sizes, int n_in,
                              void* d_out, int out_size, void* d_ws, size_t ws_size,
                              hipStream_t stream)
{
    const float* feat = (const float*)d_in[0];
    const int*   batch = (const int*)d_in[1];
    // d_in[2] = istrain (unused; dropout is identity at eval)
    const float* Wa = (const float*)d_in[3];
    const float* ba = (const float*)d_in[4];
    const float* Wb = (const float*)d_in[5];
    const float* bb = (const float*)d_in[6];
    const float* Wc = (const float*)d_in[7];
    const float* bc = (const float*)d_in[8];

    const int N = in_sizes[1];                 // 262144

    float* out_norm  = (float*)d_out;
    float* out_score = (float*)d_out + (size_t)N * DD;

    char* ws = (char*)d_ws;
    _Float16* Wab   = (_Float16*)ws;                         // 512 KB
    unsigned* smaxu = (unsigned*)(ws + 2 * LL * DD * 2);     // 64 u32
    float*    denom = (float*)(ws + 2 * LL * DD * 2 + 256);  // 64 f32

    prep_kernel<<<(2 * LL * DD + 255) / 256, 256, 0, stream>>>(Wa, Wb, Wab, smaxu, denom);
    fused_main<<<N / 32, 256, 0, stream>>>(feat, Wab, ba, bb, Wc, bc, out_norm, out_score);
    seg_max_kernel<<<512, 256, 0, stream>>>(out_score, batch, smaxu, N);
    seg_exp_kernel<<<512, 256, 0, stream>>>(out_score, batch, smaxu, denom, N);
    seg_div_kernel<<<512, 256, 0, stream>>>(out_score, batch, denom, N);
}